// Round 1
// baseline (774.800 us; speedup 1.0000x reference)
//
#include <hip/hip_runtime.h>

#define EPS 1e-5f
#define SCALE 0.17677669529663687f   // 1/sqrt(32)

typedef __attribute__((ext_vector_type(8))) short bf16x8;
typedef __attribute__((ext_vector_type(4))) float f32x4;

__device__ __forceinline__ unsigned short f2bf(float f) {
  unsigned u = __float_as_uint(f);
  return (unsigned short)((u + 0x7FFFu + ((u >> 16) & 1u)) >> 16);
}
__device__ __forceinline__ float bf2f(unsigned short h) {
  return __uint_as_float(((unsigned)h) << 16);
}

// ---------------- Kernel A: DynamicPosBias MLP -> posT[6][945] ----------------
__global__ void pos_mlp_kernel(const float* __restrict__ rpe,
                               const float* __restrict__ pw0, const float* __restrict__ pb0,
                               const float* __restrict__ g1, const float* __restrict__ be1,
                               const float* __restrict__ w1, const float* __restrict__ b1,
                               const float* __restrict__ g2, const float* __restrict__ be2,
                               const float* __restrict__ w2, const float* __restrict__ b2,
                               const float* __restrict__ g3, const float* __restrict__ be3,
                               const float* __restrict__ w3, const float* __restrict__ b3,
                               float* __restrict__ posT) {
  int r = blockIdx.x * blockDim.x + threadIdx.x;
  if (r >= 945) return;
  float a = rpe[2 * r], c = rpe[2 * r + 1];
  float x[12], y[12];
#pragma unroll
  for (int i = 0; i < 12; ++i) x[i] = pw0[2 * i] * a + pw0[2 * i + 1] * c + pb0[i];

  auto stage = [&](const float* g, const float* be, const float* w, const float* bb,
                   const float* in, float* outv, int dout) {
    float m = 0.f;
#pragma unroll
    for (int i = 0; i < 12; ++i) m += in[i];
    m *= (1.f / 12.f);
    float v = 0.f;
#pragma unroll
    for (int i = 0; i < 12; ++i) { float d = in[i] - m; v += d * d; }
    v *= (1.f / 12.f);
    float rs = rsqrtf(v + EPS);
    float t[12];
#pragma unroll
    for (int i = 0; i < 12; ++i) t[i] = fmaxf((in[i] - m) * rs * g[i] + be[i], 0.f);
    for (int o = 0; o < dout; ++o) {
      float s = bb[o];
#pragma unroll
      for (int i = 0; i < 12; ++i) s += w[o * 12 + i] * t[i];
      outv[o] = s;
    }
  };
  stage(g1, be1, w1, b1, x, y, 12);
  stage(g2, be2, w2, b2, y, x, 12);
  stage(g3, be3, w3, b3, x, y, 6);
#pragma unroll
  for (int h = 0; h < 6; ++h) posT[h * 945 + r] = y[h];
}

// ---------------- Kernel B: gather rpb_bf16[6][256*256] ----------------
__global__ void rpb_gather_kernel(const int* __restrict__ rpi, const float* __restrict__ posT,
                                  unsigned short* __restrict__ rpb) {
  int n2 = blockIdx.x * 256 + threadIdx.x;  // 65536 total
  int idx = rpi[n2];
#pragma unroll
  for (int h = 0; h < 6; ++h) rpb[h * 65536 + n2] = f2bf(posT[h * 945 + idx]);
}

// ---------------- Kernel C: mask f32 -> bf16 ----------------
__global__ void mask_cvt_kernel(const float4* __restrict__ src, uint2* __restrict__ dst, int n4) {
  int i = blockIdx.x * 256 + threadIdx.x;
  if (i >= n4) return;
  float4 v = src[i];
  uint2 o;
  o.x = (unsigned)f2bf(v.x) | ((unsigned)f2bf(v.y) << 16);
  o.y = (unsigned)f2bf(v.z) | ((unsigned)f2bf(v.w) << 16);
  dst[i] = o;
}

// ---------------- Main attention kernel ----------------
// grid = (512 windows, 6 heads), block = 256 threads (4 waves).
// LDS: Kb[256][40] bf16 (20480B) + Vt[32][264] bf16 (16896B) + Pl[4][64][40] bf16 (20480B) = 57856B
template <int USEBF>
__global__ __launch_bounds__(256, 2) void attn_kernel(
    const float* __restrict__ qkv, const float* __restrict__ maskf,
    const unsigned short* __restrict__ maskb, const unsigned short* __restrict__ rpb,
    float* __restrict__ out) {
  __shared__ unsigned short Kb[10240];  // [row 256][40]
  __shared__ unsigned short Vt[8448];   // [col 32][264]
  __shared__ unsigned short Pl[10240];  // [wave 4][row 64][40]

  const int tid = threadIdx.x;
  const int wv = tid >> 6;
  const int lane = tid & 63;
  const int quad = lane >> 4;
  const int l16 = lane & 15;
  const int wIdx = blockIdx.x, h = blockIdx.y;
  const int b = wIdx >> 7, wimg = wIdx & 127;
  const int wh = wimg >> 3, ww = wimg & 7;

  // ---- stage K and V^T into LDS (bf16) ----
  {
    const int rbase = tid >> 3;       // 0..31
    const int c4 = (tid & 7) << 2;    // 0,4,...,28
#pragma unroll
    for (int p = 0; p < 8; ++p) {
      int n = (p << 5) + rbase;                       // token index
      int l = ((wh << 3) + p) * 256 + (ww << 5) + rbase;
      const float* kp = qkv + ((4 + b) * 32768 + l) * 192 + h * 32 + c4;
      const float* vp = qkv + ((8 + b) * 32768 + l) * 192 + h * 32 + c4;
      float4 kk = *(const float4*)kp;
      float4 vvv = *(const float4*)vp;
      unsigned long long pk = (unsigned long long)f2bf(kk.x) |
                              ((unsigned long long)f2bf(kk.y) << 16) |
                              ((unsigned long long)f2bf(kk.z) << 32) |
                              ((unsigned long long)f2bf(kk.w) << 48);
      *(unsigned long long*)(&Kb[n * 40 + c4]) = pk;
      Vt[(c4 + 0) * 264 + n] = f2bf(vvv.x);
      Vt[(c4 + 1) * 264 + n] = f2bf(vvv.y);
      Vt[(c4 + 2) * 264 + n] = f2bf(vvv.z);
      Vt[(c4 + 3) * 264 + n] = f2bf(vvv.w);
    }
  }

  // ---- load Q fragments (A-layout: A[m=l16][k=quad*8+j]), scaled ----
  bf16x8 qf[4];
#pragma unroll
  for (int rt = 0; rt < 4; ++rt) {
    int n = (wv << 6) + (rt << 4) + l16;
    int i = n >> 5, j = n & 31;
    int l = ((wh << 3) + i) * 256 + (ww << 5) + j;
    const float* qp = qkv + ((0 + b) * 32768 + l) * 192 + h * 32 + (quad << 3);
    float4 a0 = *(const float4*)qp;
    float4 a1 = *(const float4*)(qp + 4);
    bf16x8 f;
    f[0] = (short)f2bf(a0.x * SCALE); f[1] = (short)f2bf(a0.y * SCALE);
    f[2] = (short)f2bf(a0.z * SCALE); f[3] = (short)f2bf(a0.w * SCALE);
    f[4] = (short)f2bf(a1.x * SCALE); f[5] = (short)f2bf(a1.y * SCALE);
    f[6] = (short)f2bf(a1.z * SCALE); f[7] = (short)f2bf(a1.w * SCALE);
    qf[rt] = f;
  }

  __syncthreads();

  f32x4 Oacc[4][2];
#pragma unroll
  for (int rt = 0; rt < 4; ++rt) {
    Oacc[rt][0] = (f32x4){0.f, 0.f, 0.f, 0.f};
    Oacc[rt][1] = (f32x4){0.f, 0.f, 0.f, 0.f};
  }
  float lsum[4][4] = {};

  const unsigned short* rpbh = rpb + (h << 16);
  const float* mfp0 = maskf + (wimg << 16);
  const unsigned short* mbp0 = maskb + (wimg << 16);
  const f32x4 zero = (f32x4){0.f, 0.f, 0.f, 0.f};

  // ---- main loop over 8 column chunks of 32 keys ----
  for (int cc = 0; cc < 8; ++cc) {
    const int cb = cc << 5;
    // K B-operand frags: B[k=quad*8+j][n=l16] = K[col][k]
    bf16x8 kf0 = *(const bf16x8*)(&Kb[(cb + l16) * 40 + (quad << 3)]);
    bf16x8 kf1 = *(const bf16x8*)(&Kb[(cb + 16 + l16) * 40 + (quad << 3)]);
    f32x4 S[4][2];
#pragma unroll
    for (int rt = 0; rt < 4; ++rt) {
      S[rt][0] = __builtin_amdgcn_mfma_f32_16x16x32_bf16(qf[rt], kf0, zero, 0, 0, 0);
      S[rt][1] = __builtin_amdgcn_mfma_f32_16x16x32_bf16(qf[rt], kf1, zero, 0, 0, 0);
    }
    // bias + exp + P write (C-layout: row = quad*4+reg, col = l16)
#pragma unroll
    for (int rt = 0; rt < 4; ++rt) {
      int row0 = (wv << 6) + (rt << 4) + (quad << 2);
      int boff = row0 * 256 + cb + l16;
      unsigned short* plp = &Pl[wv * 2560 + ((rt << 4) + (quad << 2)) * 40 + l16];
#pragma unroll
      for (int ct = 0; ct < 2; ++ct) {
#pragma unroll
        for (int r = 0; r < 4; ++r) {
          int off = boff + r * 256 + ct * 16;
          float bias;
          if (USEBF) bias = bf2f(mbp0[off]);
          else       bias = mfp0[off];
          bias += bf2f(rpbh[off]);
          float e = __expf(S[rt][ct][r] + bias);
          lsum[rt][r] += e;
          plp[r * 40 + ct * 16] = f2bf(e);
        }
      }
    }
    // P A-frags (round-trip through LDS) and V B-frags, then PV MFMAs
    bf16x8 pf[4];
#pragma unroll
    for (int rt = 0; rt < 4; ++rt)
      pf[rt] = *(const bf16x8*)(&Pl[wv * 2560 + ((rt << 4) + l16) * 40 + (quad << 3)]);
    bf16x8 vf0 = *(const bf16x8*)(&Vt[l16 * 264 + cb + (quad << 3)]);
    bf16x8 vf1 = *(const bf16x8*)(&Vt[(16 + l16) * 264 + cb + (quad << 3)]);
#pragma unroll
    for (int rt = 0; rt < 4; ++rt) {
      Oacc[rt][0] = __builtin_amdgcn_mfma_f32_16x16x32_bf16(pf[rt], vf0, Oacc[rt][0], 0, 0, 0);
      Oacc[rt][1] = __builtin_amdgcn_mfma_f32_16x16x32_bf16(pf[rt], vf1, Oacc[rt][1], 0, 0, 0);
    }
  }

  // ---- finalize: row-sum reduce across the 16 col-lanes, divide, store ----
#pragma unroll
  for (int rt = 0; rt < 4; ++rt) {
    int n0 = (wv << 6) + (rt << 4) + (quad << 2);
#pragma unroll
    for (int r = 0; r < 4; ++r) {
      float v = lsum[rt][r];
      v += __shfl_xor(v, 1);
      v += __shfl_xor(v, 2);
      v += __shfl_xor(v, 4);
      v += __shfl_xor(v, 8);
      float inv = 1.0f / v;
      int n = n0 + r;
      int i = n >> 5, j = n & 31;
      int o = ((b * 128 + (wh << 3) + i) * 256 + (ww << 5) + j) * 192 + h * 32 + l16;
      out[o] = Oacc[rt][0][r] * inv;
      out[o + 16] = Oacc[rt][1][r] * inv;
    }
  }
}

extern "C" void kernel_launch(void* const* d_in, const int* in_sizes, int n_in,
                              void* d_out, int out_size, void* d_ws, size_t ws_size,
                              hipStream_t stream) {
  const float* qkv = (const float*)d_in[0];
  const float* mask = (const float*)d_in[1];
  const float* rpe = (const float*)d_in[2];
  const float* pw0 = (const float*)d_in[3];
  const float* pb0 = (const float*)d_in[4];
  const float* g1 = (const float*)d_in[5];
  const float* be1 = (const float*)d_in[6];
  const float* w1 = (const float*)d_in[7];
  const float* b1 = (const float*)d_in[8];
  const float* g2 = (const float*)d_in[9];
  const float* be2 = (const float*)d_in[10];
  const float* w2 = (const float*)d_in[11];
  const float* b2 = (const float*)d_in[12];
  const float* g3 = (const float*)d_in[13];
  const float* be3 = (const float*)d_in[14];
  const float* w3 = (const float*)d_in[15];
  const float* b3 = (const float*)d_in[16];
  const int* rpi = (const int*)d_in[17];
  float* out = (float*)d_out;

  char* ws = (char*)d_ws;
  float* posT = (float*)ws;                                    // 6*945*4 = 22680 B
  unsigned short* rpb = (unsigned short*)(ws + 22784);         // 786432 B
  unsigned short* mb = (unsigned short*)(ws + 22784 + 786432); // 16777216 B
  const size_t need_mb = 22784 + 786432 + 16777216;
  const int use_bf = (ws_size >= need_mb) ? 1 : 0;

  pos_mlp_kernel<<<4, 256, 0, stream>>>(rpe, pw0, pb0, g1, be1, w1, b1, g2, be2, w2, b2,
                                        g3, be3, w3, b3, posT);
  rpb_gather_kernel<<<256, 256, 0, stream>>>(rpi, posT, rpb);
  if (use_bf) {
    int n4 = (128 * 256 * 256) / 4;
    mask_cvt_kernel<<<(n4 + 255) / 256, 256, 0, stream>>>((const float4*)mask, (uint2*)mb, n4);
  }

  dim3 grid(512, 6);
  if (use_bf)
    attn_kernel<1><<<grid, 256, 0, stream>>>(qkv, mask, mb, rpb, out);
  else
    attn_kernel<0><<<grid, 256, 0, stream>>>(qkv, mask, mb, rpb, out);
}

// Round 2
// 541.500 us; speedup vs baseline: 1.4308x; 1.4308x over previous
//
#include <hip/hip_runtime.h>

#define EPS 1e-5f
#define SCALE 0.17677669529663687f   // 1/sqrt(32)

typedef __attribute__((ext_vector_type(8))) short bf16x8;
typedef __attribute__((ext_vector_type(4))) float f32x4;

__device__ __forceinline__ unsigned short f2bf(float f) {
  unsigned u = __float_as_uint(f);
  return (unsigned short)((u + 0x7FFFu + ((u >> 16) & 1u)) >> 16);
}
__device__ __forceinline__ float bf2f(unsigned short h) {
  return __uint_as_float(((unsigned)h) << 16);
}
__device__ __forceinline__ float bflo(unsigned u) { return __uint_as_float(u << 16); }
__device__ __forceinline__ float bfhi(unsigned u) { return __uint_as_float(u & 0xFFFF0000u); }

// swizzled bias index: row 0..255, col 0..255 ->
// (row>>2)*1024 + (col>>5)*128 + (col&15)*8 + ((col>>4)&1)*4 + (row&3)
__device__ __forceinline__ int bias_sidx(int row, int col) {
  return ((row >> 2) << 10) + ((col >> 5) << 7) + ((col & 15) << 3) + (((col >> 4) & 1) << 2) + (row & 3);
}

// ---------------- Kernel A: DynamicPosBias MLP -> posT[6][945] ----------------
__global__ void pos_mlp_kernel(const float* __restrict__ rpe,
                               const float* __restrict__ pw0, const float* __restrict__ pb0,
                               const float* __restrict__ g1, const float* __restrict__ be1,
                               const float* __restrict__ w1, const float* __restrict__ b1,
                               const float* __restrict__ g2, const float* __restrict__ be2,
                               const float* __restrict__ w2, const float* __restrict__ b2,
                               const float* __restrict__ g3, const float* __restrict__ be3,
                               const float* __restrict__ w3, const float* __restrict__ b3,
                               float* __restrict__ posT) {
  int r = blockIdx.x * blockDim.x + threadIdx.x;
  if (r >= 945) return;
  float a = rpe[2 * r], c = rpe[2 * r + 1];
  float x[12], y[12];
#pragma unroll
  for (int i = 0; i < 12; ++i) x[i] = pw0[2 * i] * a + pw0[2 * i + 1] * c + pb0[i];

  auto stage = [&](const float* g, const float* be, const float* w, const float* bb,
                   const float* in, float* outv, int dout) {
    float m = 0.f;
#pragma unroll
    for (int i = 0; i < 12; ++i) m += in[i];
    m *= (1.f / 12.f);
    float v = 0.f;
#pragma unroll
    for (int i = 0; i < 12; ++i) { float d = in[i] - m; v += d * d; }
    v *= (1.f / 12.f);
    float rs = rsqrtf(v + EPS);
    float t[12];
#pragma unroll
    for (int i = 0; i < 12; ++i) t[i] = fmaxf((in[i] - m) * rs * g[i] + be[i], 0.f);
    for (int o = 0; o < dout; ++o) {
      float s = bb[o];
#pragma unroll
      for (int i = 0; i < 12; ++i) s += w[o * 12 + i] * t[i];
      outv[o] = s;
    }
  };
  stage(g1, be1, w1, b1, x, y, 12);
  stage(g2, be2, w2, b2, y, x, 12);
  stage(g3, be3, w3, b3, x, y, 6);
#pragma unroll
  for (int h = 0; h < 6; ++h) posT[h * 945 + r] = y[h];
}

// ---------------- Kernel B: gather rpb bf16 into swizzled layout ----------------
__global__ void rpb_gather_swz(const int* __restrict__ rpi, const float* __restrict__ posT,
                               unsigned short* __restrict__ rpb) {
  int n2 = blockIdx.x * 256 + threadIdx.x;  // 65536 total
  int row = n2 >> 8, col = n2 & 255;
  int idx = rpi[n2];
  int s = bias_sidx(row, col);
#pragma unroll
  for (int h = 0; h < 6; ++h) rpb[(h << 16) + s] = f2bf(posT[h * 945 + idx]);
}

// ---------------- Kernel C: mask f32 -> bf16 swizzled ----------------
// one thread per output dwordx4 (8 ushorts): covers rows rg*4..+3, cols cc*32+ct*16+l16
__global__ void mask_cvt_swz(const float* __restrict__ src, uint4* __restrict__ dst) {
  int g = blockIdx.x * 256 + threadIdx.x;  // 1048576 total
  int wimg = g >> 13;
  int rem = g & 8191;
  int rg = rem >> 7;
  int cc = (rem >> 4) & 7;
  int l16 = rem & 15;
  const float* m = src + (wimg << 16);
  unsigned v[8];
#pragma unroll
  for (int ct = 0; ct < 2; ++ct)
#pragma unroll
    for (int r = 0; r < 4; ++r)
      v[ct * 4 + r] = f2bf(m[(rg * 4 + r) * 256 + cc * 32 + ct * 16 + l16]);
  uint4 o;
  o.x = v[0] | (v[1] << 16);
  o.y = v[2] | (v[3] << 16);
  o.z = v[4] | (v[5] << 16);
  o.w = v[6] | (v[7] << 16);
  dst[(wimg << 13) + (rg << 7) + (cc << 4) + l16] = o;
}

// ---------------- Main attention kernel ----------------
// grid = (512 windows, 6 heads), block = 512 threads (8 waves, 32 rows/wave).
// LDS: Kb[256][40] (20480B) + Vt[32][264] token-pair-permuted (16896B)
//      + Pl 8 waves x [32][40] (20480B) = 57856B -> 2 blocks/CU, 16 waves/CU
template <int USEBF>
__global__ __launch_bounds__(512, 4) void attn_kernel(
    const float* __restrict__ qkv, const float* __restrict__ maskf,
    const unsigned short* __restrict__ maskb, const unsigned short* __restrict__ rpb,
    float* __restrict__ out) {
  __shared__ unsigned short Kb[10240];  // [tok 256][40]
  __shared__ unsigned short Vt[8448];   // [ch 32][264], tokens pair-permuted
  __shared__ unsigned short Pl[10240];  // [wave 8][row 32][40], k' pair-permuted

  const int tid = threadIdx.x;
  const int wv = tid >> 6;
  const int lane = tid & 63;
  const int quad = lane >> 4;
  const int l16 = lane & 15;
  const int wIdx = blockIdx.x, h = blockIdx.y;
  const int b = wIdx >> 7, wimg = wIdx & 127;
  const int wh = wimg >> 3, ww = wimg & 7;

  // ---- stage K and permuted V^T into LDS (bf16) ----
  {
    const int tok = tid >> 3;         // 0..63
    const int c4 = (tid & 7) << 2;    // 0,4,...,28
#pragma unroll
    for (int p = 0; p < 4; ++p) {
      int n = (p << 6) + tok;
      int i = n >> 5, j = n & 31;
      int l = ((wh << 3) + i) * 256 + (ww << 5) + j;
      const float* kp = qkv + ((size_t)((4 + b) * 32768 + l)) * 192 + h * 32 + c4;
      const float* vp = qkv + ((size_t)((8 + b) * 32768 + l)) * 192 + h * 32 + c4;
      float4 kk = *(const float4*)kp;
      float4 vvv = *(const float4*)vp;
      unsigned long long pk = (unsigned long long)f2bf(kk.x) |
                              ((unsigned long long)f2bf(kk.y) << 16) |
                              ((unsigned long long)f2bf(kk.z) << 32) |
                              ((unsigned long long)f2bf(kk.w) << 48);
      *(unsigned long long*)(&Kb[n * 40 + c4]) = pk;
      int tokp = (n & ~31) | (((n & 15) << 1) + ((n >> 4) & 1));  // pair permutation
      Vt[(c4 + 0) * 264 + tokp] = f2bf(vvv.x);
      Vt[(c4 + 1) * 264 + tokp] = f2bf(vvv.y);
      Vt[(c4 + 2) * 264 + tokp] = f2bf(vvv.z);
      Vt[(c4 + 3) * 264 + tokp] = f2bf(vvv.w);
    }
  }

  // ---- load Q fragments (A-layout: A[m=l16][k=quad*8+j]), scaled ----
  bf16x8 qf[2];
#pragma unroll
  for (int rt = 0; rt < 2; ++rt) {
    int n = (wv << 5) + (rt << 4) + l16;
    int i = n >> 5, j = n & 31;
    int l = ((wh << 3) + i) * 256 + (ww << 5) + j;
    const float* qp = qkv + ((size_t)(b * 32768 + l)) * 192 + h * 32 + (quad << 3);
    float4 a0 = *(const float4*)qp;
    float4 a1 = *(const float4*)(qp + 4);
    bf16x8 f;
    f[0] = (short)f2bf(a0.x * SCALE); f[1] = (short)f2bf(a0.y * SCALE);
    f[2] = (short)f2bf(a0.z * SCALE); f[3] = (short)f2bf(a0.w * SCALE);
    f[4] = (short)f2bf(a1.x * SCALE); f[5] = (short)f2bf(a1.y * SCALE);
    f[6] = (short)f2bf(a1.z * SCALE); f[7] = (short)f2bf(a1.w * SCALE);
    qf[rt] = f;
  }

  __syncthreads();

  f32x4 Oacc[2][2];
#pragma unroll
  for (int rt = 0; rt < 2; ++rt) {
    Oacc[rt][0] = (f32x4){0.f, 0.f, 0.f, 0.f};
    Oacc[rt][1] = (f32x4){0.f, 0.f, 0.f, 0.f};
  }
  float lsum[2][4] = {};

  const uint4* mb4 = (const uint4*)maskb + ((size_t)wimg << 13);
  const uint4* rb4 = (const uint4*)rpb + ((size_t)h << 13);
  const float* mfp0 = maskf + ((size_t)wimg << 16);
  unsigned short* Plw = &Pl[wv * 1280];
  const f32x4 zero = (f32x4){0.f, 0.f, 0.f, 0.f};

  for (int cc = 0; cc < 8; ++cc) {
    const int cb = cc << 5;
    // bias vector loads (issued early; independent of MFMAs)
    uint4 mu[2], ru[2];
#pragma unroll
    for (int rt = 0; rt < 2; ++rt) {
      int rg = (wv << 3) + (rt << 2) + quad;           // row>>2
      int bidx = (rg << 7) + (cc << 4) + l16;          // dwordx4 index
      ru[rt] = rb4[bidx];
      if (USEBF) mu[rt] = mb4[bidx];
    }
    // K B-operand frags
    bf16x8 kf0 = *(const bf16x8*)(&Kb[(cb + l16) * 40 + (quad << 3)]);
    bf16x8 kf1 = *(const bf16x8*)(&Kb[(cb + 16 + l16) * 40 + (quad << 3)]);
    f32x4 S[2][2];
#pragma unroll
    for (int rt = 0; rt < 2; ++rt) {
      S[rt][0] = __builtin_amdgcn_mfma_f32_16x16x32_bf16(qf[rt], kf0, zero, 0, 0, 0);
      S[rt][1] = __builtin_amdgcn_mfma_f32_16x16x32_bf16(qf[rt], kf1, zero, 0, 0, 0);
    }
    // bias + exp + packed P write
#pragma unroll
    for (int rt = 0; rt < 2; ++rt) {
      float m0[4], m1[4], p0[4], p1[4];
      if (USEBF) {
        m0[0] = bflo(mu[rt].x); m0[1] = bfhi(mu[rt].x); m0[2] = bflo(mu[rt].y); m0[3] = bfhi(mu[rt].y);
        m1[0] = bflo(mu[rt].z); m1[1] = bfhi(mu[rt].z); m1[2] = bflo(mu[rt].w); m1[3] = bfhi(mu[rt].w);
      } else {
        int row0 = (wv << 5) + (rt << 4) + (quad << 2);
#pragma unroll
        for (int r = 0; r < 4; ++r) {
          m0[r] = mfp0[(row0 + r) * 256 + cb + l16];
          m1[r] = mfp0[(row0 + r) * 256 + cb + 16 + l16];
        }
      }
      p0[0] = bflo(ru[rt].x); p0[1] = bfhi(ru[rt].x); p0[2] = bflo(ru[rt].y); p0[3] = bfhi(ru[rt].y);
      p1[0] = bflo(ru[rt].z); p1[1] = bfhi(ru[rt].z); p1[2] = bflo(ru[rt].w); p1[3] = bfhi(ru[rt].w);
#pragma unroll
      for (int r = 0; r < 4; ++r) {
        float e0 = __expf(S[rt][0][r] + m0[r] + p0[r]);
        float e1 = __expf(S[rt][1][r] + m1[r] + p1[r]);
        lsum[rt][r] += e0 + e1;
        unsigned pw = (unsigned)f2bf(e0) | ((unsigned)f2bf(e1) << 16);
        *(unsigned*)(&Plw[((rt << 4) + (quad << 2) + r) * 40 + (l16 << 1)]) = pw;
      }
    }
    // P A-frags (per-wave LDS round trip) + permuted V B-frags
    bf16x8 pf[2];
#pragma unroll
    for (int rt = 0; rt < 2; ++rt)
      pf[rt] = *(const bf16x8*)(&Plw[((rt << 4) + l16) * 40 + (quad << 3)]);
    bf16x8 vf0 = *(const bf16x8*)(&Vt[l16 * 264 + cb + (quad << 3)]);
    bf16x8 vf1 = *(const bf16x8*)(&Vt[(16 + l16) * 264 + cb + (quad << 3)]);
#pragma unroll
    for (int rt = 0; rt < 2; ++rt) {
      Oacc[rt][0] = __builtin_amdgcn_mfma_f32_16x16x32_bf16(pf[rt], vf0, Oacc[rt][0], 0, 0, 0);
      Oacc[rt][1] = __builtin_amdgcn_mfma_f32_16x16x32_bf16(pf[rt], vf1, Oacc[rt][1], 0, 0, 0);
    }
  }

  // ---- finalize ----
#pragma unroll
  for (int rt = 0; rt < 2; ++rt) {
    int n0 = (wv << 5) + (rt << 4) + (quad << 2);
#pragma unroll
    for (int r = 0; r < 4; ++r) {
      float v = lsum[rt][r];
      v += __shfl_xor(v, 1);
      v += __shfl_xor(v, 2);
      v += __shfl_xor(v, 4);
      v += __shfl_xor(v, 8);
      float inv = 1.0f / v;
      int n = n0 + r;
      int i = n >> 5, j = n & 31;
      size_t o = ((size_t)((b * 128 + (wh << 3) + i) * 256 + (ww << 5) + j)) * 192 + h * 32 + l16;
      out[o] = Oacc[rt][0][r] * inv;
      out[o + 16] = Oacc[rt][1][r] * inv;
    }
  }
}

extern "C" void kernel_launch(void* const* d_in, const int* in_sizes, int n_in,
                              void* d_out, int out_size, void* d_ws, size_t ws_size,
                              hipStream_t stream) {
  const float* qkv = (const float*)d_in[0];
  const float* mask = (const float*)d_in[1];
  const float* rpe = (const float*)d_in[2];
  const float* pw0 = (const float*)d_in[3];
  const float* pb0 = (const float*)d_in[4];
  const float* g1 = (const float*)d_in[5];
  const float* be1 = (const float*)d_in[6];
  const float* w1 = (const float*)d_in[7];
  const float* b1 = (const float*)d_in[8];
  const float* g2 = (const float*)d_in[9];
  const float* be2 = (const float*)d_in[10];
  const float* w2 = (const float*)d_in[11];
  const float* b2 = (const float*)d_in[12];
  const float* g3 = (const float*)d_in[13];
  const float* be3 = (const float*)d_in[14];
  const float* w3 = (const float*)d_in[15];
  const float* b3 = (const float*)d_in[16];
  const int* rpi = (const int*)d_in[17];
  float* out = (float*)d_out;

  char* ws = (char*)d_ws;
  float* posT = (float*)ws;                                    // 22680 B
  unsigned short* rpb = (unsigned short*)(ws + 22784);         // 786432 B (swizzled)
  unsigned short* mb = (unsigned short*)(ws + 22784 + 786432); // 16777216 B (swizzled)
  const size_t need_mb = 22784 + 786432 + 16777216;
  const int use_bf = (ws_size >= need_mb) ? 1 : 0;

  pos_mlp_kernel<<<4, 256, 0, stream>>>(rpe, pw0, pb0, g1, be1, w1, b1, g2, be2, w2, b2,
                                        g3, be3, w3, b3, posT);
  rpb_gather_swz<<<256, 256, 0, stream>>>(rpi, posT, rpb);
  if (use_bf)
    mask_cvt_swz<<<4096, 256, 0, stream>>>(mask, (uint4*)mb);

  dim3 grid(512, 6);
  if (use_bf)
    attn_kernel<1><<<grid, 512, 0, stream>>>(qkv, mask, mb, rpb, out);
  else
    attn_kernel<0><<<grid, 512, 0, stream>>>(qkv, mask, mb, rpb, out);
}